// Round 7
// baseline (16.485 us; speedup 1.0000x reference)
//
#include <hip/hip_runtime.h>

static constexpr int HID = 64;
static constexpr int M   = 63;            // intervals; knots 0..63 = one wave
static constexpr int NK  = 64;
static constexpr int OVPT  = 8;           // outputs per thread (K2)
static constexpr int OTPB  = 256;
static constexpr int OTILE = OTPB * OVPT; // 2048 outputs per block

__device__ __forceinline__ float softplusf(float x) {
  return (x > 20.0f) ? x : log1pf(expf(x));
}

// fast tanh via hardware exp + rcp: tanh(x) = 1 - 2/(e^{2x}+1). rel err ~1e-7.
__device__ __forceinline__ float fast_tanhf(float x) {
  float e = __expf(2.0f * x);
  return 1.0f - 2.0f * __builtin_amdgcn_rcpf(e + 1.0f);
}

// ---------------- K1: one block, MLP only -> beta[64] ----------------
//  W2 staged to LDS in one fully-parallel coalesced float4 round; layer-1
//  activations transposed in LDS; thread (knot=tid>>4, 4 units) k-loop over
//  LDS broadcasts; 16-lane shfl reduce; jq==0 stores beta. No Picard tail.
__global__ void __launch_bounds__(1024)
mlp_beta_kernel(const float* __restrict__ W1, const float* __restrict__ b1,
                const float* __restrict__ W2, const float* __restrict__ b2,
                const float* __restrict__ W3, const float* __restrict__ b3,
                float* __restrict__ beta_out) {
  __shared__ float W2s[HID * HID];   // 16 KB
  __shared__ float h1T[HID * NK];    // 16 KB, [k][knot]

  const int tid = threadIdx.x;
  const float h = 1.0f / (float)M;

  // stage W2: one coalesced float4 per thread (4096 floats)
  ((float4*)W2s)[tid] = ((const float4*)W2)[tid];

  // h1T: idx = r*1024+tid -> k = idx>>6 (wave-uniform), knot = idx&63 (=lane)
#pragma unroll
  for (int r = 0; r < 4; ++r) {
    int idx = r * 1024 + tid;
    int k = idx >> 6;
    int knot = idx & 63;
    h1T[k * NK + knot] = fast_tanhf(fmaf((float)knot * h, W1[k], b1[k]));
  }
  __syncthreads();

  const int knot = tid >> 4;
  const int jq   = tid & 15;
  const int j0   = jq * 4;
  float4 bb = *(const float4*)(b2 + j0);
  float z0 = bb.x, z1 = bb.y, z2 = bb.z, z3 = bb.w;
#pragma unroll 8
  for (int k = 0; k < HID; ++k) {
    float hk = h1T[k * NK + knot];                   // broadcast
    float4 w = *(const float4*)(W2s + k * HID + j0); // b128, conflict-free
    z0 = fmaf(hk, w.x, z0); z1 = fmaf(hk, w.y, z1);
    z2 = fmaf(hk, w.z, z2); z3 = fmaf(hk, w.w, z3);
  }
  float4 w3v = *(const float4*)(W3 + j0);
  float acc = fast_tanhf(z0) * w3v.x + fast_tanhf(z1) * w3v.y
            + fast_tanhf(z2) * w3v.z + fast_tanhf(z3) * w3v.w;
  acc += __shfl_xor(acc, 1);
  acc += __shfl_xor(acc, 2);
  acc += __shfl_xor(acc, 4);
  acc += __shfl_xor(acc, 8);
  if (jq == 0) beta_out[knot] = softplusf(acc + b3[0]);
}

// ---------------- K2: per-wave Picard + output ----------------
// Each wave independently: load beta[lane], run 7 Picard half-passes in
// registers (lane p = knot p, 4th-order cumulative quadrature), write its
// qg row (= Q_I - g*t, linear fold exact under cubic interp) to a private
// LDS segment (no barrier: within-wave LDS ordering), then each thread
// cubic-interpolates 8 outputs and stores two float4s.
__global__ void __launch_bounds__(OTPB)
picard_output_kernel(const float* __restrict__ beta_g,
                     const float* __restrict__ I_init,
                     const float* __restrict__ gamma_param,
                     float* __restrict__ out, int T) {
  __shared__ float qw[(OTPB / 64) * NK];   // one 64-float row per wave

  const int tid  = threadIdx.x;
  const int lane = tid & 63;
  const int wid  = tid >> 6;

  const float I0 = I_init[0];
  const float S0 = 1.0f - I0;
  const float g  = softplusf(gamma_param[0]);
  const float h  = 1.0f / (float)M;

  // ---- per-wave register Picard (lane p = knot p) ----
  const int p = lane;
  const float tp = (float)p * h;
  const float bet = beta_g[p];             // 256 B, L2-broadcast
  const float c24 = h * (1.0f / 24.0f);
  float QA = 0.0f, QB = 0.0f;
  const int im2 = p >= 2 ? p - 2 : 0;
  const int im1 = p >= 1 ? p - 1 : 0;
  const int ip1 = p <= 62 ? p + 1 : 63;
  const int ip2 = p <= 61 ? p + 2 : 63;
  const int ip3 = p <= 60 ? p + 3 : 63;
#pragma unroll
  for (int ph = 0; ph < 7; ++ph) {
    const bool iPass = (ph & 1) == 0;
    float f = iPass ? (bet * S0 * __expf(-QA))
                    : (bet * I0 * __expf(QB - g * tp));
    float fm2 = __shfl(f, im2);
    float fm1 = __shfl(f, im1);
    float f1  = __shfl(f, ip1);
    float f2  = __shfl(f, ip2);
    float f3  = __shfl(f, ip3);
    float e;
    if (p == 0)       e = 9.0f*f + 19.0f*f1 - 5.0f*f2 + f3;     // AM start
    else if (p < 62)  e = 13.0f*(f + f1) - fm1 - f2;            // interior
    else if (p == 62) e = fm2 - 5.0f*fm1 + 19.0f*f + 9.0f*f1;   // AM end
    else              e = 0.0f;                                 // lane 63
    e *= c24;
    float incl = e;
#pragma unroll
    for (int off = 1; off < 64; off <<= 1) {
      float w = __shfl_up(incl, off);
      if (p >= off) incl += w;
    }
    float Q = incl - e;                    // exclusive prefix = Q at knot p
    if (iPass) QB = Q; else QA = Q;
  }
  float* qrow = qw + wid * NK;
  qrow[p] = QB - g * tp;                   // wave-private row, no barrier

  // ---- output slice: cubic-Lagrange interp from qrow ----
  const float scale = (float)M / (float)T;
  int o0 = blockIdx.x * OTILE + tid * OVPT;
  float r[OVPT];
#pragma unroll
  for (int u = 0; u < OVPT; ++u) {
    int i = o0 + u;
    float pos = (float)(i + 1) * scale;            // (0, M]
    int js = (int)pos - 1;
    js = js < 0 ? 0 : (js > M - 3 ? M - 3 : js);   // [0, 60]
    float x = pos - (float)js;                     // [0, 3]
    float xm1 = x - 1.0f, xm2 = x - 2.0f, xm3 = x - 3.0f;
    float w0 = -(xm1 * xm2 * xm3) * (1.0f / 6.0f);
    float w1 =  (x   * xm2 * xm3) * 0.5f;
    float w2 = -(x   * xm1 * xm3) * 0.5f;
    float w3 =  (x   * xm1 * xm2) * (1.0f / 6.0f);
    float qv = w0 * qrow[js]     + w1 * qrow[js + 1]
             + w2 * qrow[js + 2] + w3 * qrow[js + 3];
    r[u] = I0 * __expf(qv);
  }
  if (o0 + OVPT <= T) {
    float4* o4 = (float4*)(out + o0);
    o4[0] = make_float4(r[0], r[1], r[2], r[3]);
    o4[1] = make_float4(r[4], r[5], r[6], r[7]);
  } else {
#pragma unroll
    for (int u = 0; u < OVPT; ++u) {
      int i = o0 + u;
      if (i < T) out[i] = r[u];
    }
  }
}

extern "C" void kernel_launch(void* const* d_in, const int* in_sizes, int n_in,
                              void* d_out, int out_size, void* d_ws, size_t ws_size,
                              hipStream_t stream) {
  const float* I0 = (const float*)d_in[1];
  const float* W1 = (const float*)d_in[2];
  const float* b1 = (const float*)d_in[3];
  const float* W2 = (const float*)d_in[4];
  const float* b2 = (const float*)d_in[5];
  const float* W3 = (const float*)d_in[6];
  const float* b3 = (const float*)d_in[7];
  const float* gp = (const float*)d_in[8];
  float* out = (float*)d_out;
  int T = in_sizes[0];

  float* beta = (float*)d_ws;                      // [NK]

  hipLaunchKernelGGL(mlp_beta_kernel, dim3(1), dim3(1024), 0, stream,
                     W1, b1, W2, b2, W3, b3, beta);

  int blocks = (T + OTILE - 1) / OTILE;            // 245
  hipLaunchKernelGGL(picard_output_kernel, dim3(blocks), dim3(OTPB), 0, stream,
                     beta, I0, gp, out, T);
}

// Round 8
// 14.729 us; speedup vs baseline: 1.1192x; 1.1192x over previous
//
#include <hip/hip_runtime.h>

static constexpr int HID = 64;
static constexpr int M   = 63;            // intervals; knots 0..63 = one wave
static constexpr int NK  = 64;
static constexpr int TPB = 1024;
static constexpr int OVPT  = 4;           // outputs per thread
static constexpr int OTILE = TPB * OVPT;  // 4096 outputs per block

__device__ __forceinline__ float softplusf(float x) {
  return (x > 20.0f) ? x : log1pf(expf(x));
}

// fast tanh via hardware exp + rcp: tanh(x) = 1 - 2/(e^{2x}+1). rel err ~1e-7.
__device__ __forceinline__ float fast_tanhf(float x) {
  float e = __expf(2.0f * x);
  return 1.0f - 2.0f * __builtin_amdgcn_rcpf(e + 1.0f);
}

// ONE kernel, 123 blocks x 1024 threads. Each block redundantly computes the
// 64-knot solution (identical fp32 work -> deterministic), then writes its own
// 4096-output slice. Kept SMALL-CODE (rolled loops) to avoid the R5 I$ thrash:
//  1. W2 -> LDS in one fully-parallel coalesced float4 round (16 KB).
//  2. h1T[k][knot] = tanh(t*W1+b1) transposed in LDS.
//  3. layer2+3 GEMM from LDS (b128 16-addr reads = 2-way = free; broadcasts).
//  4. wave 0: 7 Picard half-passes in registers (lane p = knot p, 4th-order
//     cumulative quadrature); writes qg[p] = Q_I(t_p) - g*t_p to LDS.
//  5. all threads: cubic-Lagrange interp of qg + exp, float4 store.
__global__ void __launch_bounds__(TPB)
sir_onekernel(const float* __restrict__ I_init,
              const float* __restrict__ W1, const float* __restrict__ b1,
              const float* __restrict__ W2, const float* __restrict__ b2,
              const float* __restrict__ W3, const float* __restrict__ b3,
              const float* __restrict__ gamma_param,
              float* __restrict__ out, int T) {
  __shared__ float W2s[HID * HID];   // 16 KB
  __shared__ float h1T[HID * NK];    // 16 KB, [k][knot]
  __shared__ float beta_s[NK];
  __shared__ float qg[NK];

  const int tid = threadIdx.x;
  const float h = 1.0f / (float)M;

  // ---- stage W2: one coalesced float4 per thread (4096 floats) ----
  ((float4*)W2s)[tid] = ((const float4*)W2)[tid];

  // ---- layer 1: consecutive tid -> consecutive LDS addr, conflict-free ----
#pragma unroll
  for (int r = 0; r < 4; ++r) {
    int idx = r * 1024 + tid;
    int k = idx >> 6;
    int knot = idx & 63;
    h1T[idx] = fast_tanhf(fmaf((float)knot * h, W1[k], b1[k]));
  }
  __syncthreads();

  // ---- layers 2+3: thread -> (knot = tid>>4, 4 units j0 = 4*(tid&15)) ----
  {
    const int knot = tid >> 4;
    const int jq   = tid & 15;
    const int j0   = jq * 4;
    float4 bb = *(const float4*)(b2 + j0);
    float z0 = bb.x, z1 = bb.y, z2 = bb.z, z3 = bb.w;
#pragma unroll 8
    for (int k = 0; k < HID; ++k) {
      float hk = h1T[k * NK + knot];                   // broadcast
      float4 w = *(const float4*)(W2s + k * HID + j0); // 16 addrs, 2-way free
      z0 = fmaf(hk, w.x, z0); z1 = fmaf(hk, w.y, z1);
      z2 = fmaf(hk, w.z, z2); z3 = fmaf(hk, w.w, z3);
    }
    float4 w3v = *(const float4*)(W3 + j0);
    float acc = fast_tanhf(z0) * w3v.x + fast_tanhf(z1) * w3v.y
              + fast_tanhf(z2) * w3v.z + fast_tanhf(z3) * w3v.w;
    acc += __shfl_xor(acc, 1);
    acc += __shfl_xor(acc, 2);
    acc += __shfl_xor(acc, 4);
    acc += __shfl_xor(acc, 8);
    if (jq == 0) beta_s[knot] = softplusf(acc + b3[0]);
  }
  __syncthreads();

  const float I0 = I_init[0];
  const float g  = softplusf(gamma_param[0]);

  // ---- Picard on wave 0 only (serial path; other waves wait ~0.7 us) ----
  if (tid < 64) {
    const float S0 = 1.0f - I0;
    const int p = tid;
    const float tp = (float)p * h;
    const float bet = beta_s[p];
    const float c24 = h * (1.0f / 24.0f);
    float QA = 0.0f, QB = 0.0f;
    const int im2 = p >= 2 ? p - 2 : 0;
    const int im1 = p >= 1 ? p - 1 : 0;
    const int ip1 = p <= 62 ? p + 1 : 63;
    const int ip2 = p <= 61 ? p + 2 : 63;
    const int ip3 = p <= 60 ? p + 3 : 63;
    for (int ph = 0; ph < 7; ++ph) {
      const bool iPass = (ph & 1) == 0;
      float f = iPass ? (bet * S0 * __expf(-QA))
                      : (bet * I0 * __expf(QB - g * tp));
      float fm2 = __shfl(f, im2);
      float fm1 = __shfl(f, im1);
      float f1  = __shfl(f, ip1);
      float f2  = __shfl(f, ip2);
      float f3  = __shfl(f, ip3);
      float e;
      if (p == 0)       e = 9.0f*f + 19.0f*f1 - 5.0f*f2 + f3;     // AM start
      else if (p < 62)  e = 13.0f*(f + f1) - fm1 - f2;            // interior
      else if (p == 62) e = fm2 - 5.0f*fm1 + 19.0f*f + 9.0f*f1;   // AM end
      else              e = 0.0f;                                 // lane 63
      e *= c24;
      float incl = e;
#pragma unroll
      for (int off = 1; off < 64; off <<= 1) {
        float w = __shfl_up(incl, off);
        if (p >= off) incl += w;
      }
      float Q = incl - e;                    // exclusive prefix = Q at knot p
      if (iPass) QB = Q; else QA = Q;
    }
    qg[p] = QB - g * tp;   // fold linear term: exact under cubic interp
  }
  __syncthreads();

  // ---- output slice: cubic-Lagrange interp of qg + exp ----
  const float scale = (float)M / (float)T;
  int o0 = blockIdx.x * OTILE + tid * OVPT;
  float r[OVPT];
#pragma unroll
  for (int u = 0; u < OVPT; ++u) {
    int i = o0 + u;
    float pos = (float)(i + 1) * scale;            // (0, M]
    int js = (int)pos - 1;
    js = js < 0 ? 0 : (js > M - 3 ? M - 3 : js);   // [0, 60]
    float x = pos - (float)js;                     // [0, 3]
    float xm1 = x - 1.0f, xm2 = x - 2.0f, xm3 = x - 3.0f;
    float w0 = -(xm1 * xm2 * xm3) * (1.0f / 6.0f);
    float w1 =  (x   * xm2 * xm3) * 0.5f;
    float w2 = -(x   * xm1 * xm3) * 0.5f;
    float w3 =  (x   * xm1 * xm2) * (1.0f / 6.0f);
    float qv = w0 * qg[js]     + w1 * qg[js + 1]
             + w2 * qg[js + 2] + w3 * qg[js + 3];
    r[u] = I0 * __expf(qv);
  }
  if (o0 + OVPT <= T) {
    *(float4*)(out + o0) = make_float4(r[0], r[1], r[2], r[3]);
  } else {
#pragma unroll
    for (int u = 0; u < OVPT; ++u) {
      int i = o0 + u;
      if (i < T) out[i] = r[u];
    }
  }
}

extern "C" void kernel_launch(void* const* d_in, const int* in_sizes, int n_in,
                              void* d_out, int out_size, void* d_ws, size_t ws_size,
                              hipStream_t stream) {
  const float* I0 = (const float*)d_in[1];
  const float* W1 = (const float*)d_in[2];
  const float* b1 = (const float*)d_in[3];
  const float* W2 = (const float*)d_in[4];
  const float* b2 = (const float*)d_in[5];
  const float* W3 = (const float*)d_in[6];
  const float* b3 = (const float*)d_in[7];
  const float* gp = (const float*)d_in[8];
  float* out = (float*)d_out;
  int T = in_sizes[0];

  int blocks = (T + OTILE - 1) / OTILE;            // 123
  hipLaunchKernelGGL(sir_onekernel, dim3(blocks), dim3(TPB), 0, stream,
                     I0, W1, b1, W2, b2, W3, b3, gp, out, T);
}